// Round 6
// baseline (418.020 us; speedup 1.0000x reference)
//
#include <hip/hip_runtime.h>

// Problem constants
#define B_    32
#define S_    4096
#define CIN   21
#define DM    512
#define KW    8
#define NK    74
#define PROJIN 1534      // 73*21 + 1
#define CP    24         // channels padded to 24
#define KSEG  192        // KW*CP per half (hi or lo)

// Tiling
#define WT    256        // w per block (4 waves x 64)
#define DTB   128        // d per block (n=8 frags, all waves same d-range)
#define SROWS 263        // x rows staged = WT + 7
#define R_    265        // allocated rows (odd -> LDS bank spread)

typedef __attribute__((ext_vector_type(8))) short bf16x8;
typedef __attribute__((ext_vector_type(4))) float f32x4;

__device__ __forceinline__ unsigned short f2bf_rne(float x) {
  unsigned u = __float_as_uint(x);
  unsigned r = (u + 0x7FFFu + ((u >> 16) & 1u)) >> 16;
  return (unsigned short)r;
}
__device__ __forceinline__ float bf2f(unsigned short b) {
  return __uint_as_float(((unsigned)b) << 16);
}

// ---------------------------------------------------------------------------
// W_eff[d][k*24+c] = sum_{n<73} proj_w[d,n*21+c]*kernels[n,k]
//                    + (c==0)*proj_w[d,1533]*kernels[73,k];  c>=21 -> 0
// bf16 hi/lo halves, row-major [512][192] each. (Validated round 5.)
// ---------------------------------------------------------------------------
__global__ __launch_bounds__(256) void build_weff(
    const float* __restrict__ kernels, const float* __restrict__ proj_w,
    unsigned short* __restrict__ wh, unsigned short* __restrict__ wl) {
  __shared__ float pw[PROJIN];
  __shared__ float kk[NK * KW];
  const int d = blockIdx.x, tid = threadIdx.x;
  for (int i = tid; i < PROJIN; i += 256) pw[i] = proj_w[d * PROJIN + i];
  for (int i = tid; i < NK * KW; i += 256) kk[i] = kernels[i];
  __syncthreads();
  if (tid < KSEG) {
    const int k = tid / CP, c = tid % CP;
    float acc = 0.f;
    if (c < CIN) {
      #pragma unroll 1
      for (int n = 0; n < 73; ++n)
        acc = fmaf(pw[n * CIN + c], kk[n * KW + k], acc);
      if (c == 0) acc = fmaf(pw[PROJIN - 1], kk[73 * KW + k], acc);
    }
    const unsigned short h = f2bf_rne(acc);
    wh[d * KSEG + tid] = h;
    wl[d * KSEG + tid] = f2bf_rne(acc - bf2f(h));
  }
}

// ---------------------------------------------------------------------------
// out[b,d,w] = proj_b[d] + sum WhiXhi + WhiXlo + WloXhi  (single pass).
// Block: 4 waves, tile 256w x 128d. Wave: 64w (m=4) x 128d (n=8).
// X in LDS: transposed 16B-granule planes [hi/lo][cgroup 0..2][row].
// W streamed per-fragment from global (L2-resident weff). No main-loop barriers.
// ---------------------------------------------------------------------------
__global__ __launch_bounds__(256, 2) void conv_mfma2(
    const float* __restrict__ x, const unsigned short* __restrict__ wh,
    const unsigned short* __restrict__ wl, const float* __restrict__ proj_b,
    float* __restrict__ out) {
  __shared__ __align__(16) unsigned short Xt[2 * 3 * R_ * 8];  // 25,440 B

  const int tid = threadIdx.x;
  const int blk = blockIdx.x;
  const int dt = blk & 3;
  const int wt = (blk >> 2) & 15;
  const int b  = blk >> 6;
  const int d0 = dt * DTB;
  const int w0 = wt * WT;

  // ---- stage x slab (row s <-> global w = w0-7+s), fp32 -> bf16 hi/lo ----
  const float* xb = x + (size_t)b * (S_ * CIN);
  for (int i = tid; i < SROWS * CP; i += 256) {
    const int s = i / CP, c = i - s * CP;
    const int wg = w0 - 7 + s;
    float v = 0.f;
    if (c < CIN && wg >= 0) v = xb[wg * CIN + c];
    const unsigned short h = f2bf_rne(v);
    const unsigned short lo = f2bf_rne(v - bf2f(h));
    const int g = c >> 3, e = c & 7;
    Xt[(g * R_ + s) * 8 + e] = h;            // hi plane
    Xt[((3 + g) * R_ + s) * 8 + e] = lo;     // lo plane (+3*R_ granules)
  }
  __syncthreads();

  const int l    = tid & 63;
  const int wave = tid >> 6;
  const int l15  = l & 15;
  const int q    = l >> 4;
  const int q8   = q * 8;

  // per-step granule-offset addend for this lane's quarter:
  // kappa0 = 32s + 8q -> tap k = /24, channel c0 = %24 (always mult of 8)
  int koff[6];
  #pragma unroll
  for (int s = 0; s < 6; ++s) {
    const int k0 = 32 * s + q8;
    const int k = k0 / CP, c0 = k0 - k * CP;
    koff[s] = (c0 >> 3) * R_ + k;
  }
  const int rowb = wave * 64 + l15;                 // + m*16 + k = slab row
  const int wrow = (d0 + l15) * KSEG + q8;          // + n*16*KSEG + s*32

  f32x4 acc[4][8] = {};

  #pragma unroll
  for (int s = 0; s < 6; ++s) {
    bf16x8 fh[4], fl[4];
    #pragma unroll
    for (int m = 0; m < 4; ++m) {
      const int gi = koff[s] + rowb + m * 16;       // granule index (hi)
      fh[m] = *(const bf16x8*)&Xt[gi * 8];
      fl[m] = *(const bf16x8*)&Xt[(gi + 3 * R_) * 8];
    }
    #pragma unroll
    for (int half = 0; half < 2; ++half) {
      bf16x8 fwh[4], fwl[4];
      #pragma unroll
      for (int j = 0; j < 4; ++j) {
        const int n = half * 4 + j;
        const int off = wrow + n * (16 * KSEG) + s * 32;
        fwh[j] = *(const bf16x8*)&wh[off];
        fwl[j] = *(const bf16x8*)&wl[off];
      }
      #pragma unroll
      for (int m = 0; m < 4; ++m)
        #pragma unroll
        for (int j = 0; j < 4; ++j) {
          const int n = half * 4 + j;
          acc[m][n] = __builtin_amdgcn_mfma_f32_16x16x32_bf16(
              fh[m], fwh[j], acc[m][n], 0, 0, 0);
          acc[m][n] = __builtin_amdgcn_mfma_f32_16x16x32_bf16(
              fl[m], fwh[j], acc[m][n], 0, 0, 0);
          acc[m][n] = __builtin_amdgcn_mfma_f32_16x16x32_bf16(
              fh[m], fwl[j], acc[m][n], 0, 0, 0);
        }
    }
  }

  // ---- epilogue: bias + float4 stores (D row = q*4+reg -> consecutive w) ----
  const size_t ob = (size_t)b * DM * S_;
  #pragma unroll
  for (int n = 0; n < 8; ++n) {
    const int d = d0 + n * 16 + l15;
    const float bias = proj_b[d];
    #pragma unroll
    for (int m = 0; m < 4; ++m) {
      const int w = w0 + wave * 64 + m * 16 + q * 4;
      f32x4 v = acc[m][n];
      v = v + bias;
      *(f32x4*)&out[ob + (size_t)d * S_ + w] = v;
    }
  }
}

// ---------------------------------------------------------------------------
extern "C" void kernel_launch(void* const* d_in, const int* in_sizes, int n_in,
                              void* d_out, int out_size, void* d_ws, size_t ws_size,
                              hipStream_t stream) {
  const float* x       = (const float*)d_in[0];
  const float* kernels = (const float*)d_in[1];
  const float* proj_w  = (const float*)d_in[2];
  const float* proj_b  = (const float*)d_in[3];
  float* out = (float*)d_out;

  unsigned short* weff_hi = (unsigned short*)d_ws;          // [512][192] u16
  unsigned short* weff_lo = weff_hi + (size_t)DM * KSEG;

  build_weff<<<DM, 256, 0, stream>>>(kernels, proj_w, weff_hi, weff_lo);
  conv_mfma2<<<B_ * 16 * 4, 256, 0, stream>>>(x, weff_hi, weff_lo, proj_b, out);
}

// Round 7
// 346.782 us; speedup vs baseline: 1.2054x; 1.2054x over previous
//
#include <hip/hip_runtime.h>

// Problem constants
#define B_    32
#define S_    4096
#define CIN   21
#define DM    512
#define KW    8
#define NK    74
#define PROJIN 1534      // 73*21 + 1
#define CP    24         // channels padded to 24

// conv tiling
#define DTB   32         // d per block (16 d-tiles)
#define CW    512        // w per chunk
#define NCH   8          // chunks per block (8*512 = 4096)
#define ROWCH 519        // x rows per chunk slab (CW + 7)
#define ROWP  4104       // padded x rows in xt (4096 + 7 + 1 align)
#define WGRAN 1584       // W image granules per d-tile: 2*6*4*33
#define XGRAN (6*ROWCH)  // 3114 granules staged per chunk (hi/lo x 3 cgroups)

typedef __attribute__((ext_vector_type(8))) short bf16x8;
typedef __attribute__((ext_vector_type(4))) float f32x4;

__device__ __forceinline__ unsigned short f2bf_rne(float x) {
  unsigned u = __float_as_uint(x);
  return (unsigned short)((u + 0x7FFFu + ((u >> 16) & 1u)) >> 16);
}
__device__ __forceinline__ float bf2f(unsigned short b) {
  return __uint_as_float(((unsigned)b) << 16);
}

#define MFMA16 __builtin_amdgcn_mfma_f32_16x16x32_bf16
#define GLOAD16(gsrc, ldst)                                              \
  __builtin_amdgcn_global_load_lds(                                      \
      (const __attribute__((address_space(1))) unsigned int*)(gsrc),     \
      (__attribute__((address_space(3))) unsigned int*)(ldst), 16, 0, 0)

// ---------------------------------------------------------------------------
// W_eff[d][kappa], kappa = 32s+8q+e, (k,c) = (kappa/24, kappa%24):
//   = sum_{n<73} proj_w[d,n*21+c]*kernels[n,k] + (c==0)*proj_w[d,1533]*kernels[73,k]
// bf16 hi/lo, written directly in the conv kernel's LDS image layout:
//   wimg[dt][ ((h*6+s)*4+q)*33 + (d&31) ][e]   (16B granules, 33-pad per q)
// ---------------------------------------------------------------------------
__global__ __launch_bounds__(256) void build_weff3(
    const float* __restrict__ kernels, const float* __restrict__ proj_w,
    unsigned short* __restrict__ wimg) {
  __shared__ float pw[PROJIN];
  __shared__ float kk[NK * KW];
  const int d = blockIdx.x, tid = threadIdx.x;
  for (int i = tid; i < PROJIN; i += 256) pw[i] = proj_w[d * PROJIN + i];
  for (int i = tid; i < NK * KW; i += 256) kk[i] = kernels[i];
  __syncthreads();
  if (tid < 192) {
    const int kap = tid;
    const int k = kap / CP, c = kap - k * CP;
    float acc = 0.f;
    if (c < CIN) {
      #pragma unroll 1
      for (int n = 0; n < 73; ++n)
        acc = fmaf(pw[n * CIN + c], kk[n * KW + k], acc);
      if (c == 0) acc = fmaf(pw[PROJIN - 1], kk[73 * KW + k], acc);
    }
    const unsigned short h = f2bf_rne(acc);
    const unsigned short lo = f2bf_rne(acc - bf2f(h));
    const int s = kap >> 5, q = (kap >> 3) & 3, e = kap & 7;
    const size_t base = (size_t)(d >> 5) * WGRAN * 8;
    const int dloc = d & 31;
    wimg[base + ((size_t)((s * 4 + q) * 33 + dloc)) * 8 + e] = h;
    wimg[base + ((size_t)(((6 + s) * 4 + q) * 33 + dloc)) * 8 + e] = lo;
  }
}

// ---------------------------------------------------------------------------
// x [32][4096][21] fp32 -> xt [b][h(2)][g(3)][ROWP][8] bf16 granules.
// Padded row i <-> global w = i-7 (zeros for i<7, i>4102); c = g*8+e (c>=21 -> 0).
// One thread per 16B granule -> fully coalesced granule writes.
// ---------------------------------------------------------------------------
__global__ __launch_bounds__(256) void build_xt(
    const float* __restrict__ x, unsigned short* __restrict__ xt) {
  const int t = blockIdx.x * 256 + threadIdx.x;   // granule id (grid exact)
  const int b = t / (6 * ROWP);
  int rem = t - b * 6 * ROWP;
  const int pg = rem / ROWP;                      // 0..5 = h*3+g
  const int row = rem - pg * ROWP;
  const int h = pg / 3, g = pg % 3;
  const int w = row - 7;
  bf16x8 o;
  #pragma unroll
  for (int e = 0; e < 8; ++e) {
    const int c = g * 8 + e;
    float v = 0.f;
    if (w >= 0 && w < S_ && c < CIN) v = x[((size_t)b * S_ + w) * CIN + c];
    const unsigned short hi = f2bf_rne(v);
    o[e] = (short)(h ? f2bf_rne(v - bf2f(hi)) : hi);
  }
  *(bf16x8*)&xt[(size_t)t * 8] = o;
}

// ---------------------------------------------------------------------------
// Main conv: block = (b, 32-d slice), marches w in 8 chunks of 512.
// 8 waves: wave wg owns w-range [wg*64, wg*64+64) (m=4 frags) x all 32 d (n=2).
// X (hi/lo) + W (hi/lo) in LDS only; staging via global_load_lds DMA.
// Stores: nontemporal float4, sequential along w per d-row across chunks.
// ---------------------------------------------------------------------------
__global__ __launch_bounds__(512, 4) void conv3(
    const unsigned short* __restrict__ wimg,
    const unsigned short* __restrict__ xt,
    const float* __restrict__ proj_b, float* __restrict__ out) {
  extern __shared__ __align__(16) char smem[];
  unsigned short* Xl = (unsigned short*)smem;                 // 3114 granules
  unsigned short* Wl = (unsigned short*)(smem + XGRAN * 16);  // 1584 granules

  const int tid = threadIdx.x;
  const int p = blockIdx.x;
  const int xcd = p & 7, slot = p >> 3;     // XCD-cluster: 4 b-values per XCD
  const int b = xcd * 4 + (slot >> 4);
  const int dt = slot & 15;
  const int d0 = dt * DTB;

  // ---- one-time: stage W image (DMA) ----
  const unsigned short* wsrc = wimg + (size_t)dt * WGRAN * 8;
  for (int i = tid; i < WGRAN; i += 512)
    GLOAD16(wsrc + (size_t)i * 8, Wl + (size_t)i * 8);
  // ---- stage X chunk 0 (DMA) ----
  const unsigned short* xb = xt + (size_t)b * 6 * ROWP * 8;
  for (int i = tid; i < XGRAN; i += 512) {
    const int pg = i / ROWCH, r = i - pg * ROWCH;
    GLOAD16(xb + ((size_t)pg * ROWP + r) * 8, Xl + (size_t)i * 8);
  }

  const int l = tid & 63;
  const int wg = tid >> 6;                  // 0..7 w-group
  const int l15 = l & 15;
  const int q = l >> 4;
  const int q8 = q * 8;

  int koff[6];
  #pragma unroll
  for (int s = 0; s < 6; ++s) {             // kappa0 = 32s+8q -> (k, c0)
    const int k0 = 32 * s + q8;
    const int k = k0 / CP, c0 = k0 - k * CP;
    koff[s] = (c0 >> 3) * ROWCH + k;        // granule addend: g-plane + tap
  }
  const int xrow = wg * 64 + l15;
  const int wq = q * 33 + l15;
  const float bias0 = proj_b[d0 + l15];
  const float bias1 = proj_b[d0 + 16 + l15];
  const size_t ob = (size_t)b * DM * S_;

  for (int c = 0; c < NCH; ++c) {
    asm volatile("s_waitcnt vmcnt(0)" ::: "memory");  // staging DMA done
    __syncthreads();

    f32x4 acc[4][2] = {};
    #pragma unroll
    for (int s = 0; s < 6; ++s) {
      const int wgr = s * 132 + wq;
      const bf16x8 fw0h = *(const bf16x8*)&Wl[(size_t)wgr * 8];
      const bf16x8 fw1h = *(const bf16x8*)&Wl[(size_t)(wgr + 16) * 8];
      const bf16x8 fw0l = *(const bf16x8*)&Wl[(size_t)(wgr + 792) * 8];
      const bf16x8 fw1l = *(const bf16x8*)&Wl[(size_t)(wgr + 808) * 8];
      #pragma unroll
      for (int m = 0; m < 4; ++m) {
        const int xg = koff[s] + xrow + m * 16;
        const bf16x8 fh = *(const bf16x8*)&Xl[(size_t)xg * 8];
        const bf16x8 fl = *(const bf16x8*)&Xl[(size_t)(xg + 1557) * 8];
        acc[m][0] = MFMA16(fh, fw0h, acc[m][0], 0, 0, 0);
        acc[m][0] = MFMA16(fl, fw0h, acc[m][0], 0, 0, 0);
        acc[m][0] = MFMA16(fh, fw0l, acc[m][0], 0, 0, 0);
        acc[m][1] = MFMA16(fh, fw1h, acc[m][1], 0, 0, 0);
        acc[m][1] = MFMA16(fl, fw1h, acc[m][1], 0, 0, 0);
        acc[m][1] = MFMA16(fh, fw1l, acc[m][1], 0, 0, 0);
      }
    }
    __syncthreads();                        // all LDS reads done

    if (c + 1 < NCH) {                      // issue next chunk DMA (no wait)
      const size_t cb = (size_t)(c + 1) * CW;
      for (int i = tid; i < XGRAN; i += 512) {
        const int pg = i / ROWCH, r = i - pg * ROWCH;
        GLOAD16(xb + ((size_t)pg * ROWP + cb + r) * 8, Xl + (size_t)i * 8);
      }
    }

    // stores for chunk c (overlap the DMA latency); nontemporal
    #pragma unroll
    for (int nd = 0; nd < 2; ++nd) {
      const int d = d0 + nd * 16 + l15;
      const float bias = nd ? bias1 : bias0;
      float* orow = out + ob + (size_t)d * S_ + c * CW + wg * 64 + q * 4;
      #pragma unroll
      for (int m = 0; m < 4; ++m) {
        f32x4 v = acc[m][nd] + bias;
        __builtin_nontemporal_store(v, (f32x4*)(orow + m * 16));
      }
    }
  }
}

// ---------------------------------------------------------------------------
extern "C" void kernel_launch(void* const* d_in, const int* in_sizes, int n_in,
                              void* d_out, int out_size, void* d_ws, size_t ws_size,
                              hipStream_t stream) {
  const float* x       = (const float*)d_in[0];
  const float* kernels = (const float*)d_in[1];
  const float* proj_w  = (const float*)d_in[2];
  const float* proj_b  = (const float*)d_in[3];
  float* out = (float*)d_out;

  unsigned short* wimg = (unsigned short*)d_ws;            // 16*1584*16B = 405,504B
  unsigned short* xt   = wimg + (size_t)16 * WGRAN * 8;    // 32*6*4104*16B = 12.6MB

  build_weff3<<<DM, 256, 0, stream>>>(kernels, proj_w, wimg);
  build_xt<<<(B_ * 6 * ROWP) / 256, 256, 0, stream>>>(x, xt);

  (void)hipFuncSetAttribute((const void*)conv3,
                            hipFuncAttributeMaxDynamicSharedMemorySize,
                            (XGRAN + WGRAN) * 16);
  conv3<<<512, 512, (XGRAN + WGRAN) * 16, stream>>>(wimg, xt, proj_b, out);
}